// Round 6
// baseline (136.795 us; speedup 1.0000x reference)
//
#include <hip/hip_runtime.h>
#include <hip/hip_bf16.h>
#include <stdint.h>

// Conv2d: x[128][256][256] (f32), w[256][128][3][3] (f32), bias[256] (f32)
// out[256][256][256] (f32).  pad=1, stride=1.
// bf16 MFMA implicit GEMM: M=COUT=256, N=65536 pixels, K=9 taps x 128 ch = 1152.
//   ws: x_p bf16 [258][258][128] (padded, channel-innermost), W_pk bf16 [9][256][128].
//
// R8 (post-mortem R7: counted-vmcnt gained only 2.5us; per-tile 5880 cyc vs MFMA
// 2483 -- barrier-locked waves alternate LDS-read/MFMA phases instead of
// overlapping; ~12us is the exposed HBM-write epilogue. Attack the MFMA floor):
//   - Switch to v_mfma_f32_32x32x16_bf16: 2495 TF vs 2075 TF measured rate ->
//     MFMA per tile 2483 -> 2066 cyc (-17%), SAME ds_read count (24 b128/wave/
//     tile), half the MFMA instruction count.
//   - Fragment map (family pattern, verified 16x16 analog): A row=l&31,
//     k=(l>>5)*8+j; C/D col=lane&31, row=(reg&3)+8*(reg>>2)+4*(lane>>5).
//   - Existing XOR swizzle stays conflict-free for 32-row reads (quarter-wave
//     spans 8 physical octets -> balanced banks). Gate: SQ_LDS_BANK_CONFLICT.
//   - Phases relabel to (m-pair x k-pair); stage FIFO {A0,A2,B0..B3,A1,A3} and
//     vmcnt(2) placements identical to R7 (proven race-free).
//   - Epilogue: each store now 2x128B-contiguous segments (vs 4x64B).
// Same LDS layout / staging / swizzle / XCD swizzle / prep as R7.

#define CIN   128
#define COUT  256
#define HH    256
#define WW    256
#define HP    258
#define WP    258
#define XP_ELEMS (HP * WP * CIN)   // 8,520,192 bf16 elements

typedef __attribute__((ext_vector_type(8)))  __bf16 bf16x8;
typedef __attribute__((ext_vector_type(16))) float  floatx16;
typedef __attribute__((ext_vector_type(8)))  short  short8;

#define AS1 __attribute__((address_space(1)))
#define AS3 __attribute__((address_space(3)))

// ---------------- fused prep: xpose_pad | wpack | zero_border ----------------
__global__ __launch_bounds__(256) void prep(const float* __restrict__ x,
                                            const float* __restrict__ w,
                                            unsigned short* __restrict__ xp,
                                            unsigned short* __restrict__ wpk) {
    __shared__ __align__(16) unsigned short tile[64][136];  // xpose region only
    const int bid = blockIdx.x;
    const int t   = threadIdx.x;
    if (bid < 1024) {
        // transpose+cast x[c][h][w] -> x_p[h+1][w+1][c]
        int h  = bid >> 2;
        int w0 = (bid & 3) << 6;
        int wl = t & 63, icq = t >> 6;
        const float* src = x + h * WW + w0 + wl;
#pragma unroll
        for (int icb = 0; icb < 32; ++icb) {
            int ic = icb * 4 + icq;
            __hip_bfloat16 b = __float2bfloat16(src[ic * (HH * WW)]);
            tile[wl][ic] = __builtin_bit_cast(unsigned short, b);
        }
        __syncthreads();
        int wl2 = t >> 2, q = t & 3;    // 64 rows x 4 chunks of 64B
        const short8* s8 = (const short8*)&tile[wl2][q * 32];
        short8* d8 = (short8*)(xp + ((size_t)(h + 1) * WP + (w0 + 1) + wl2) * CIN + q * 32);
#pragma unroll
        for (int i = 0; i < 4; ++i) d8[i] = s8[i];
    } else if (bid < 2176) {
        // pack weights -> bf16 W_pk[kk][o][ic]
        int idx = (bid - 1024) * 256 + t;           // 0..294911
        int kk  = idx >> 15;
        int rem = idx & 32767;                      // o*128 + ic
        __hip_bfloat16 b = __float2bfloat16(w[rem * 9 + kk]);
        wpk[idx] = __builtin_bit_cast(unsigned short, b);
    } else {
        // zero the padded border: 1028 px x 16 octets, short8 stores
        int cid = (bid - 2176) * 256 + t;           // 0..16447
        if (cid < 16448) {
            int p = cid >> 4, oct = cid & 15;
            int hp, wp;
            if (p < 258)      { hp = 0;   wp = p; }
            else if (p < 516) { hp = 257; wp = p - 258; }
            else { int s = p - 516; hp = 1 + (s >> 1); wp = (s & 1) * 257; }
            short8 z = {0, 0, 0, 0, 0, 0, 0, 0};
            *(short8*)(xp + ((size_t)hp * WP + wp) * CIN + oct * 8) = z;
        }
    }
}

// ---------------- main: 256(M) x 256(pixels of row h), 8 waves, 18 K-tiles ----------------
// Per buffer: A[256 o][64 ch] then B[256 pix][64 ch], 16384 shorts each.
// Swizzle: physical octet = logical octet ^ (row & 7)  (octet = 16 B).
// 32x32x16 MFMA: wave tile 128x64 = 4 m-tiles x 2 n-tiles; acc floatx16[4][2].
// K-tile (BK=64) = 4 k-slices of 16; phases = (m-pair mp) x (k-pair kp).
__global__ __launch_bounds__(512, 2) void conv_mfma(
    const unsigned short* __restrict__ xp,   // [258][258][128] bf16
    const unsigned short* __restrict__ wpk,  // [9][256][128]   bf16
    const float* __restrict__ bias,          // [256] f32
    float* __restrict__ out) {               // [256][65536] f32
    __shared__ __align__(16) unsigned short x_lds[2 * 32768];   // 131,072 B

    const int tid  = threadIdx.x;            // 0..511
    const int lane = tid & 63;
    const int wv   = tid >> 6;               // 0..7
    const int l31  = lane & 31;
    const int lhi  = lane >> 5;              // 0..1
    const int r7   = l31 & 7;                // row&7 (bases are multiples of 32)
    const int wave_m = (wv >> 2) << 7;       // 0 or 128
    const int wave_n = (wv & 3) << 6;        // 0,64,128,192

    // XCD swizzle (bijective, 256 % 8 == 0): XCD k gets rows [k*32, k*32+32).
    const int orig = blockIdx.x;
    const int h    = ((orig & 7) << 5) | (orig >> 3);

    // Staging per-thread source offset: row-group tid>>3, pre-swizzled octet.
    const int soff = (tid >> 3) * CIN + ((((tid & 7) ^ ((tid >> 3) & 7))) << 3);

    // One staging load: A_i (rows i*64..) or B_i; dests lane-contiguous 16B.
#define GLD_A(nb_, src_, i_) \
    __builtin_amdgcn_global_load_lds((const AS1 void*)((src_) + (i_) * 8192), \
        (AS3 void*)((nb_) + (i_) * 4096 + tid * 8), 16, 0, 0)
#define GLD_B(nb_, src_, i_) \
    __builtin_amdgcn_global_load_lds((const AS1 void*)((src_) + (i_) * 8192), \
        (AS3 void*)((nb_) + 16384 + (i_) * 4096 + tid * 8), 16, 0, 0)

    // Swizzled fragment reads (Ab = current buffer base, shorts).
    // logical octet = kp*4 + s*2 + lhi ; physical = logical ^ r7.
#define LDA(Ab_, mbase_, kp_, s_) \
    (*(const bf16x8*)((Ab_) + (((mbase_) + l31) << 6) + ((((kp_)*4 + (s_)*2 + lhi) ^ r7) << 3)))
#define LDB(Ab_, nbase_, kp_, s_) \
    (*(const bf16x8*)((Ab_) + 16384 + (((nbase_) + l31) << 6) + ((((kp_)*4 + (s_)*2 + lhi) ^ r7) << 3)))

    floatx16 acc[4][2];
#pragma unroll
    for (int q = 0; q < 4; ++q)
#pragma unroll
        for (int nj = 0; nj < 2; ++nj)
#pragma unroll
            for (int e = 0; e < 16; ++e) acc[q][nj][e] = 0.f;

    // ---- prologue: stage tile 0 into buf 0 in FIFO order {A0,A2,B0..B3,A1,A3} ----
    {
        const unsigned short* a0  = wpk + soff;                          // kk=0, hf=0
        const unsigned short* b0s = xp + ((size_t)h * WP) * CIN + soff;  // kh=0, kw=0
        unsigned short* nb = x_lds;
        GLD_A(nb, a0, 0); GLD_A(nb, a0, 2);
        GLD_B(nb, b0s, 0); GLD_B(nb, b0s, 1); GLD_B(nb, b0s, 2); GLD_B(nb, b0s, 3);
        GLD_A(nb, a0, 1); GLD_A(nb, a0, 3);
    }
    asm volatile("s_waitcnt vmcnt(2)" ::: "memory");   // first 6 (phase-(0,*) data) landed
    __builtin_amdgcn_s_barrier();

#pragma unroll
    for (int t2 = 0; t2 < 18; ++t2) {        // K-tile = (kk, ch-half)
        const int cur = t2 & 1;
        const unsigned short* Ab = x_lds + cur * 32768;
        unsigned short* nb = x_lds + (cur ^ 1) * 32768;
        const bool hn = (t2 < 17);
        const int tn  = t2 + 1;
        const int kkn = tn >> 1, hfn = tn & 1;
        const int khn = kkn / 3, kwn = kkn - khn * 3;
        const unsigned short* asrcn = wpk + (size_t)kkn * (COUT * CIN) + hfn * 64 + soff;
        const unsigned short* bsrcn = xp + ((size_t)(h + khn) * WP + kwn) * CIN + hfn * 64 + soff;

        bf16x8 b0[2][2], b1[2][2], a[2][2];

        // ===== phase (mp=0, kp=0): rows wave_m..+63 (A0/A2) =====
#pragma unroll
        for (int nj = 0; nj < 2; ++nj)
#pragma unroll
            for (int s = 0; s < 2; ++s) b0[nj][s] = LDB(Ab, wave_n + nj * 32, 0, s);
#pragma unroll
        for (int mi = 0; mi < 2; ++mi)
#pragma unroll
            for (int s = 0; s < 2; ++s) a[mi][s] = LDA(Ab, wave_m + mi * 32, 0, s);
        if (hn) { GLD_A(nb, asrcn, 0); GLD_A(nb, asrcn, 2); }
        __builtin_amdgcn_s_barrier();
        __builtin_amdgcn_s_setprio(1);
#pragma unroll
        for (int s = 0; s < 2; ++s)
#pragma unroll
            for (int mi = 0; mi < 2; ++mi)
#pragma unroll
                for (int nj = 0; nj < 2; ++nj)
                    acc[mi][nj] = __builtin_amdgcn_mfma_f32_32x32x16_bf16(
                        a[mi][s], b0[nj][s], acc[mi][nj], 0, 0, 0);
        __builtin_amdgcn_s_setprio(0);
        if (hn) asm volatile("s_waitcnt vmcnt(2)" ::: "memory");  // this tile's A1,A3 landed
        else    asm volatile("s_waitcnt vmcnt(0)" ::: "memory");
        __builtin_amdgcn_s_barrier();

        // ===== phase (mp=1, kp=0): rows wave_m+64..+127 (A1/A3) =====
#pragma unroll
        for (int mi = 0; mi < 2; ++mi)
#pragma unroll
            for (int s = 0; s < 2; ++s) a[mi][s] = LDA(Ab, wave_m + 64 + mi * 32, 0, s);
        if (hn) { GLD_B(nb, bsrcn, 0); GLD_B(nb, bsrcn, 1); }
        __builtin_amdgcn_s_barrier();
        __builtin_amdgcn_s_setprio(1);
#pragma unroll
        for (int s = 0; s < 2; ++s)
#pragma unroll
            for (int mi = 0; mi < 2; ++mi)
#pragma unroll
                for (int nj = 0; nj < 2; ++nj)
                    acc[2 + mi][nj] = __builtin_amdgcn_mfma_f32_32x32x16_bf16(
                        a[mi][s], b0[nj][s], acc[2 + mi][nj], 0, 0, 0);
        __builtin_amdgcn_s_setprio(0);
        __builtin_amdgcn_s_barrier();

        // ===== phase (mp=0, kp=1) =====
#pragma unroll
        for (int nj = 0; nj < 2; ++nj)
#pragma unroll
            for (int s = 0; s < 2; ++s) b1[nj][s] = LDB(Ab, wave_n + nj * 32, 1, s);
#pragma unroll
        for (int mi = 0; mi < 2; ++mi)
#pragma unroll
            for (int s = 0; s < 2; ++s) a[mi][s] = LDA(Ab, wave_m + mi * 32, 1, s);
        if (hn) { GLD_B(nb, bsrcn, 2); GLD_B(nb, bsrcn, 3); }
        __builtin_amdgcn_s_barrier();
        __builtin_amdgcn_s_setprio(1);
#pragma unroll
        for (int s = 0; s < 2; ++s)
#pragma unroll
            for (int mi = 0; mi < 2; ++mi)
#pragma unroll
                for (int nj = 0; nj < 2; ++nj)
                    acc[mi][nj] = __builtin_amdgcn_mfma_f32_32x32x16_bf16(
                        a[mi][s], b1[nj][s], acc[mi][nj], 0, 0, 0);
        __builtin_amdgcn_s_setprio(0);
        __builtin_amdgcn_s_barrier();

        // ===== phase (mp=1, kp=1) =====
#pragma unroll
        for (int mi = 0; mi < 2; ++mi)
#pragma unroll
            for (int s = 0; s < 2; ++s) a[mi][s] = LDA(Ab, wave_m + 64 + mi * 32, 1, s);
        if (hn) { GLD_A(nb, asrcn, 1); GLD_A(nb, asrcn, 3); }
        __builtin_amdgcn_s_barrier();
        __builtin_amdgcn_s_setprio(1);
#pragma unroll
        for (int s = 0; s < 2; ++s)
#pragma unroll
            for (int mi = 0; mi < 2; ++mi)
#pragma unroll
                for (int nj = 0; nj < 2; ++nj)
                    acc[2 + mi][nj] = __builtin_amdgcn_mfma_f32_32x32x16_bf16(
                        a[mi][s], b1[nj][s], acc[2 + mi][nj], 0, 0, 0);
        __builtin_amdgcn_s_setprio(0);
        if (hn) asm volatile("s_waitcnt vmcnt(2)" ::: "memory");  // next tile's first 6 landed
        __builtin_amdgcn_s_barrier();
    }
#undef GLD_A
#undef GLD_B
#undef LDA
#undef LDB

    // Epilogue: 32x32 C layout: col = l31, row = (r&3) + 8*(r>>2) + 4*lhi.
    // Each store: lanes 0-31 = 128B contiguous of one row, lanes 32-63 = row+4.
    const int nbase = h * WW + wave_n + l31;
#pragma unroll
    for (int q = 0; q < 4; ++q) {
        const int mbase = wave_m + q * 32 + 4 * lhi;
#pragma unroll
        for (int r = 0; r < 16; ++r) {
            const int mrow = mbase + (r & 3) + 8 * (r >> 2);
            const float bv = bias[mrow];
#pragma unroll
            for (int nj = 0; nj < 2; ++nj)
                out[(size_t)mrow * (HH * WW) + nbase + nj * 32] = acc[q][nj][r] + bv;
        }
    }
}

extern "C" void kernel_launch(void* const* d_in, const int* in_sizes, int n_in,
                              void* d_out, int out_size, void* d_ws, size_t ws_size,
                              hipStream_t stream) {
    (void)in_sizes; (void)n_in; (void)out_size; (void)ws_size;
    const float* x    = (const float*)d_in[0];   // 128*256*256
    const float* w    = (const float*)d_in[1];   // 256*128*3*3
    const float* bias = (const float*)d_in[2];   // 256
    float* out = (float*)d_out;

    unsigned short* xp  = (unsigned short*)d_ws;            // bf16 [258][258][128]
    unsigned short* wpk = xp + XP_ELEMS;                    // bf16 [9][256][128]

    prep<<<dim3(2241), dim3(256), 0, stream>>>(x, w, xp, wpk);
    conv_mfma<<<dim3(256), dim3(512), 0, stream>>>(xp, wpk, bias, out);
}

// Round 7
// 133.069 us; speedup vs baseline: 1.0280x; 1.0280x over previous
//
#include <hip/hip_runtime.h>
#include <hip/hip_bf16.h>
#include <stdint.h>

// Conv2d: x[128][256][256] (f32), w[256][128][3][3] (f32), bias[256] (f32)
// out[256][256][256] (f32).  pad=1, stride=1.
// bf16 MFMA implicit GEMM: M=COUT=256, N=65536 pixels, K=9 taps x 128 ch = 1152.
//   ws: x_p bf16 [258][258][128] (padded, channel-innermost), W_pk bf16 [9][256][128].
//
// R9 (post-mortem R8: 32x32 frags regressed -- SQ_LDS_BANK_CONFLICT 0 -> 3.5M,
// exactly the pre-registered revert gate. Reverted to 16x16 + proven swizzle.
// R7's real wall: all 8 waves in ONE barrier domain -> LDS-read phases and MFMA
// phases alternate instead of overlapping; per-tile 5880 cyc vs 2483 MFMA):
//   - 256-thread blocks (4 waves), BM=BN=128, BK=64, LDS 64KB -> TWO independent
//     blocks co-resident per CU (128KB of 160KB). No shared barrier: one block's
//     sync/LDS-flood overlaps the other's MFMA (m114 mechanism). Same 8 waves/CU.
//   - Wave tile 64x64: (M_w+N_w)=128 vs 192 -> per-CU LDS read traffic -33%
//     (128KB+64KB wr = 192KB/tile vs 256KB). LDS pole ~2050 cyc, balanced with
//     MFMA instead of dominating.
//   - Same 16x16x32 MFMA, same 64ch-row layout + octet XOR swizzle triple
//     (linear GLD dest / pre-swizzled source / swizzled read), same per-tile
//     __syncthreads (drain masked by sibling block), same XCD banding.
// FP accumulation order identical to R6/R7 -> bit-identical output expected.

#define CIN   128
#define COUT  256
#define HH    256
#define WW    256
#define HP    258
#define WP    258
#define XP_ELEMS (HP * WP * CIN)   // 8,520,192 bf16 elements

typedef __attribute__((ext_vector_type(8))) __bf16 bf16x8;
typedef __attribute__((ext_vector_type(4))) float  floatx4;
typedef __attribute__((ext_vector_type(8))) short  short8;

#define AS1 __attribute__((address_space(1)))
#define AS3 __attribute__((address_space(3)))

// ---------------- fused prep: xpose_pad | wpack | zero_border ----------------
__global__ __launch_bounds__(256) void prep(const float* __restrict__ x,
                                            const float* __restrict__ w,
                                            unsigned short* __restrict__ xp,
                                            unsigned short* __restrict__ wpk) {
    __shared__ __align__(16) unsigned short tile[64][136];  // xpose region only
    const int bid = blockIdx.x;
    const int t   = threadIdx.x;
    if (bid < 1024) {
        // transpose+cast x[c][h][w] -> x_p[h+1][w+1][c]
        int h  = bid >> 2;
        int w0 = (bid & 3) << 6;
        int wl = t & 63, icq = t >> 6;
        const float* src = x + h * WW + w0 + wl;
#pragma unroll
        for (int icb = 0; icb < 32; ++icb) {
            int ic = icb * 4 + icq;
            __hip_bfloat16 b = __float2bfloat16(src[ic * (HH * WW)]);
            tile[wl][ic] = __builtin_bit_cast(unsigned short, b);
        }
        __syncthreads();
        int wl2 = t >> 2, q = t & 3;    // 64 rows x 4 chunks of 64B
        const short8* s8 = (const short8*)&tile[wl2][q * 32];
        short8* d8 = (short8*)(xp + ((size_t)(h + 1) * WP + (w0 + 1) + wl2) * CIN + q * 32);
#pragma unroll
        for (int i = 0; i < 4; ++i) d8[i] = s8[i];
    } else if (bid < 2176) {
        // pack weights -> bf16 W_pk[kk][o][ic]
        int idx = (bid - 1024) * 256 + t;           // 0..294911
        int kk  = idx >> 15;
        int rem = idx & 32767;                      // o*128 + ic
        __hip_bfloat16 b = __float2bfloat16(w[rem * 9 + kk]);
        wpk[idx] = __builtin_bit_cast(unsigned short, b);
    } else {
        // zero the padded border: 1028 px x 16 octets, short8 stores
        int cid = (bid - 2176) * 256 + t;           // 0..16447
        if (cid < 16448) {
            int p = cid >> 4, oct = cid & 15;
            int hp, wp;
            if (p < 258)      { hp = 0;   wp = p; }
            else if (p < 516) { hp = 257; wp = p - 258; }
            else { int s = p - 516; hp = 1 + (s >> 1); wp = (s & 1) * 257; }
            short8 z = {0, 0, 0, 0, 0, 0, 0, 0};
            *(short8*)(xp + ((size_t)hp * WP + wp) * CIN + oct * 8) = z;
        }
    }
}

// ---------------- main: 128(M) x 128(pixels), 4 waves, 18 K-tiles, 2 blocks/CU ----------------
// Per buffer (16384 shorts = 32KB): A[128 o][64 ch] at 0, B[128 px][64 ch] at 8192.
// Swizzle: physical octet = logical octet ^ (row & 7)  (octet = 16 B).
//   stage: lane writes LDS linearly (row tid>>3 per 32-row chunk, slot tid&7);
//          fetches pre-swizzled global octet (tid&7)^((tid>>3)&7).
//   read : frag (row, logical oct o) at shorts row*64 + ((o ^ (row&7))<<3).
__global__ __launch_bounds__(256, 2) void conv_mfma(
    const unsigned short* __restrict__ xp,   // [258][258][128] bf16
    const unsigned short* __restrict__ wpk,  // [9][256][128]   bf16
    const float* __restrict__ bias,          // [256] f32
    float* __restrict__ out) {               // [256][65536] f32
    __shared__ __align__(16) unsigned short x_lds[2 * 16384];   // 65,536 B

    const int tid  = threadIdx.x;            // 0..255
    const int lane = tid & 63;
    const int wv   = tid >> 6;               // 0..3
    const int l15  = lane & 15;
    const int lg   = lane >> 4;              // 0..3
    const int wave_m = (wv >> 1) << 6;       // 0 or 64
    const int wave_n = (wv & 1) << 6;        // 0 or 64

    // XCD swizzle (bijective, 1024 % 8 == 0): XCD k gets 128 consecutive swz
    // ids -> one m-half x contiguous 64-row band (xp slice ~4.3MB ~ its L2).
    const int orig = blockIdx.x;
    const int swz  = ((orig & 7) << 7) | (orig >> 3);
    const int m0 = (swz >> 9) << 7;          // 0 or 128
    const int h  = (swz >> 1) & 255;
    const int w0 = (swz & 1) << 7;           // 0 or 128

    // Staging per-thread source offset: row tid>>3 (32 rows/instr), slot tid&7,
    // pre-swizzled global octet (tid&7)^((tid>>3)&7).
    const int soff = (tid >> 3) * CIN + ((((tid & 7) ^ ((tid >> 3) & 7))) << 3);

    // One staging load: 256 thr x 16B = 4KB = 32 rows of 128B.
#define GLD_A(nb_, src_, i_) \
    __builtin_amdgcn_global_load_lds((const AS1 void*)((src_) + (i_) * 32 * CIN), \
        (AS3 void*)((nb_) + (i_) * 2048 + tid * 8), 16, 0, 0)
#define GLD_B(nb_, src_, i_) \
    __builtin_amdgcn_global_load_lds((const AS1 void*)((src_) + (i_) * 32 * CIN), \
        (AS3 void*)((nb_) + 8192 + (i_) * 2048 + tid * 8), 16, 0, 0)

    // Swizzled fragment read: rows rb+l15 (rb multiple of 16), k-slice ks.
#define LDX(base_, rb_, ks_) \
    (*(const bf16x8*)((base_) + (((rb_) + l15) << 6) + ((((ks_) * 4 + lg) ^ (l15 & 7)) << 3)))

    auto stage = [&](int buf, int kk, int kh, int kw, int hf) {
        unsigned short* nb = x_lds + buf * 16384;
        const unsigned short* asrc =
            wpk + (size_t)kk * (COUT * CIN) + (size_t)m0 * CIN + hf * 64 + soff;
        const unsigned short* bsrc =
            xp + ((size_t)(h + kh) * WP + (w0 + kw)) * CIN + hf * 64 + soff;
#pragma unroll
        for (int i = 0; i < 4; ++i) GLD_A(nb, asrc, i);
#pragma unroll
        for (int i = 0; i < 4; ++i) GLD_B(nb, bsrc, i);
    };

    floatx4 acc[4][4];
#pragma unroll
    for (int fi = 0; fi < 4; ++fi)
#pragma unroll
        for (int fj = 0; fj < 4; ++fj) {
            floatx4 z = {0.f, 0.f, 0.f, 0.f};
            acc[fi][fj] = z;
        }

    // Prologue: stage tile 0 into buffer 0; __syncthreads drains vmcnt(0).
    stage(0, 0, 0, 0, 0);
    __syncthreads();

#pragma unroll
    for (int t2 = 0; t2 < 18; ++t2) {        // K-tile = (kk, ch-half)
        const int cur = t2 & 1;
        const unsigned short* Ab = x_lds + cur * 16384;
        const unsigned short* Bb = Ab + 8192;

        // Issue next tile's stage first: 8 loads fly under this tile's compute;
        // the end-of-tile __syncthreads (vmcnt 0) finds them landed. The drain
        // stall is covered by the sibling block on this CU.
        if (t2 < 17) {
            const int tn  = t2 + 1;
            const int kkn = tn >> 1, hfn = tn & 1;
            const int khn = kkn / 3, kwn = kkn - khn * 3;
            stage(cur ^ 1, kkn, khn, kwn, hfn);
        }

#pragma unroll
        for (int ks = 0; ks < 2; ++ks) {
            bf16x8 a[4], b[4];
#pragma unroll
            for (int fj = 0; fj < 4; ++fj) b[fj] = LDX(Bb, wave_n + fj * 16, ks);
#pragma unroll
            for (int fi = 0; fi < 4; ++fi) a[fi] = LDX(Ab, wave_m + fi * 16, ks);
            __builtin_amdgcn_s_setprio(1);
#pragma unroll
            for (int fi = 0; fi < 4; ++fi)
#pragma unroll
                for (int fj = 0; fj < 4; ++fj)
                    acc[fi][fj] = __builtin_amdgcn_mfma_f32_16x16x32_bf16(
                        a[fi], b[fj], acc[fi][fj], 0, 0, 0);
            __builtin_amdgcn_s_setprio(0);
        }

        __syncthreads();   // stage writes visible + buffer reuse guarded
    }
#undef GLD_A
#undef GLD_B
#undef LDX

    // Epilogue: D row=(lane>>4)*4+reg (within 16), col=l15; add bias, store f32.
    const int nbase = h * WW + w0 + wave_n + l15;
#pragma unroll
    for (int fi = 0; fi < 4; ++fi) {
        int mrow = m0 + wave_m + fi * 16 + lg * 4;
#pragma unroll
        for (int r = 0; r < 4; ++r) {
            float bv = bias[mrow + r];
#pragma unroll
            for (int fj = 0; fj < 4; ++fj)
                out[(size_t)(mrow + r) * (HH * WW) + nbase + fj * 16] = acc[fi][fj][r] + bv;
        }
    }
}

extern "C" void kernel_launch(void* const* d_in, const int* in_sizes, int n_in,
                              void* d_out, int out_size, void* d_ws, size_t ws_size,
                              hipStream_t stream) {
    (void)in_sizes; (void)n_in; (void)out_size; (void)ws_size;
    const float* x    = (const float*)d_in[0];   // 128*256*256
    const float* w    = (const float*)d_in[1];   // 256*128*3*3
    const float* bias = (const float*)d_in[2];   // 256
    float* out = (float*)d_out;

    unsigned short* xp  = (unsigned short*)d_ws;            // bf16 [258][258][128]
    unsigned short* wpk = xp + XP_ELEMS;                    // bf16 [9][256][128]

    prep<<<dim3(2241), dim3(256), 0, stream>>>(x, w, xp, wpk);
    conv_mfma<<<dim3(1024), dim3(256), 0, stream>>>(xp, wpk, bias, out);
}